// Round 6
// baseline (87.790 us; speedup 1.0000x reference)
//
#include <hip/hip_runtime.h>
#include <math.h>

#define T_FRAMES 1025
#define TSTRIDE  1032          // row stride for Ht; 1032*8 = 129*64 -> rows 64B-aligned
#define BATCH    4
#define LWAV     131072
#define KWC      1023
#define MFFT     2048
#define PI_F     3.14159265358979323846f
#define NCONVBLK 514

struct c32 { float r, i; };
__device__ __forceinline__ c32 mkc(float r, float i){ c32 z; z.r=r; z.i=i; return z; }
__device__ __forceinline__ c32 cadd(c32 a, c32 b){ return mkc(a.r+b.r, a.i+b.i); }
__device__ __forceinline__ c32 csub(c32 a, c32 b){ return mkc(a.r-b.r, a.i-b.i); }
__device__ __forceinline__ c32 cmul(c32 a, c32 b){ return mkc(a.r*b.r - a.i*b.i, a.r*b.i + a.i*b.r); }
__device__ __forceinline__ c32 cni(c32 a){ return mkc(a.i, -a.r); }           // a * (-i)
#define C8F 0.70710678118654752440f
__device__ __forceinline__ c32 c8p(c32 a){ return mkc(C8F*(a.r+a.i), C8F*(a.i-a.r)); }   // * e^{-i pi/4}
__device__ __forceinline__ c32 c8m(c32 a){ return mkc(C8F*(a.i-a.r), -C8F*(a.r+a.i)); }  // * e^{-i 3pi/4}

// float2 <-> c32 LDS helpers
__device__ __forceinline__ void st2(float2* X, int p, c32 v){ X[p] = make_float2(v.r, v.i); }
__device__ __forceinline__ c32 ld2(const float2* X, int p){ float2 e = X[p]; return mkc(e.x, e.y); }

// pads: pX for 2048-FFT arrays; pS2 for 512-FFT frames
__device__ __forceinline__ int pX(int j){ return j + (j >> 5); }
__device__ __forceinline__ int pS2(int j){ return j + (j >> 4); }
__device__ __forceinline__ int rev9(int j){ return (int)(__brev((unsigned)j) >> 23); }

// e^{-2*pi*i*r/2048} via fast HW sincos
__device__ __forceinline__ c32 wexp(int r) {
    float s, c;
    __sincosf((float)r * (-PI_F / 1024.0f), &s, &c);
    return mkc(c, s);
}

// ---- radix-8 DIF step; w3 = W_M^{m'} of current level (M = sub-size)
__device__ __forceinline__ void dif8_tw(c32 y[8], c32 w3) {
    c32 w2 = cmul(w3, w3), w1 = cmul(w2, w2);
    c32 u[8], v[8], d;
    d = csub(y[0], y[4]); u[0] = cadd(y[0], y[4]); u[4] = cmul(d, w3);
    d = csub(y[1], y[5]); u[1] = cadd(y[1], y[5]); u[5] = c8p(cmul(d, w3));
    d = csub(y[2], y[6]); u[2] = cadd(y[2], y[6]); u[6] = cni(cmul(d, w3));
    d = csub(y[3], y[7]); u[3] = cadd(y[3], y[7]); u[7] = c8m(cmul(d, w3));
    d = csub(u[0], u[2]); v[0] = cadd(u[0], u[2]); v[2] = cmul(d, w2);
    d = csub(u[1], u[3]); v[1] = cadd(u[1], u[3]); v[3] = cni(cmul(d, w2));
    d = csub(u[4], u[6]); v[4] = cadd(u[4], u[6]); v[6] = cmul(d, w2);
    d = csub(u[5], u[7]); v[5] = cadd(u[5], u[7]); v[7] = cni(cmul(d, w2));
    d = csub(v[0], v[1]); y[0] = cadd(v[0], v[1]); y[1] = cmul(d, w1);
    d = csub(v[2], v[3]); y[2] = cadd(v[2], v[3]); y[3] = cmul(d, w1);
    d = csub(v[4], v[5]); y[4] = cadd(v[4], v[5]); y[5] = cmul(d, w1);
    d = csub(v[6], v[7]); y[6] = cadd(v[6], v[7]); y[7] = cmul(d, w1);
}
__device__ __forceinline__ void dif8_nt(c32 y[8]) {
    c32 u[8], v[8], d;
    d = csub(y[0], y[4]); u[0] = cadd(y[0], y[4]); u[4] = d;
    d = csub(y[1], y[5]); u[1] = cadd(y[1], y[5]); u[5] = c8p(d);
    d = csub(y[2], y[6]); u[2] = cadd(y[2], y[6]); u[6] = cni(d);
    d = csub(y[3], y[7]); u[3] = cadd(y[3], y[7]); u[7] = c8m(d);
    d = csub(u[0], u[2]); v[0] = cadd(u[0], u[2]); v[2] = d;
    d = csub(u[1], u[3]); v[1] = cadd(u[1], u[3]); v[3] = cni(d);
    d = csub(u[4], u[6]); v[4] = cadd(u[4], u[6]); v[6] = d;
    d = csub(u[5], u[7]); v[5] = cadd(u[5], u[7]); v[7] = cni(d);
    d = csub(v[0], v[1]); y[0] = cadd(v[0], v[1]); y[1] = d;
    d = csub(v[2], v[3]); y[2] = cadd(v[2], v[3]); y[3] = d;
    d = csub(v[4], v[5]); y[4] = cadd(v[4], v[5]); y[5] = d;
    d = csub(v[6], v[7]); y[6] = cadd(v[6], v[7]); y[7] = d;
}
__device__ __forceinline__ void dit8_tw(c32 y[8], c32 w3) {
    c32 w2 = cmul(w3, w3), w1 = cmul(w2, w2);
    c32 u[8], v[8], t;
    t = cmul(y[1], w1); u[0] = cadd(y[0], t); u[1] = csub(y[0], t);
    t = cmul(y[3], w1); u[2] = cadd(y[2], t); u[3] = csub(y[2], t);
    t = cmul(y[5], w1); u[4] = cadd(y[4], t); u[5] = csub(y[4], t);
    t = cmul(y[7], w1); u[6] = cadd(y[6], t); u[7] = csub(y[6], t);
    t = cmul(u[2], w2);      v[0] = cadd(u[0], t); v[2] = csub(u[0], t);
    t = cni(cmul(u[3], w2)); v[1] = cadd(u[1], t); v[3] = csub(u[1], t);
    t = cmul(u[6], w2);      v[4] = cadd(u[4], t); v[6] = csub(u[4], t);
    t = cni(cmul(u[7], w2)); v[5] = cadd(u[5], t); v[7] = csub(u[5], t);
    t = cmul(v[4], w3);      y[0] = cadd(v[0], t); y[4] = csub(v[0], t);
    t = c8p(cmul(v[5], w3)); y[1] = cadd(v[1], t); y[5] = csub(v[1], t);
    t = cni(cmul(v[6], w3)); y[2] = cadd(v[2], t); y[6] = csub(v[2], t);
    t = c8m(cmul(v[7], w3)); y[3] = cadd(v[3], t); y[7] = csub(v[3], t);
}
__device__ __forceinline__ void dit8_nt(c32 y[8]) {
    c32 u[8], v[8], t;
    u[0] = cadd(y[0], y[1]); u[1] = csub(y[0], y[1]);
    u[2] = cadd(y[2], y[3]); u[3] = csub(y[2], y[3]);
    u[4] = cadd(y[4], y[5]); u[5] = csub(y[4], y[5]);
    u[6] = cadd(y[6], y[7]); u[7] = csub(y[6], y[7]);
    t = u[2];      v[0] = cadd(u[0], t); v[2] = csub(u[0], t);
    t = cni(u[3]); v[1] = cadd(u[1], t); v[3] = csub(u[1], t);
    t = u[6];      v[4] = cadd(u[4], t); v[6] = csub(u[4], t);
    t = cni(u[7]); v[5] = cadd(u[5], t); v[7] = csub(u[5], t);
    t = v[4];      y[0] = cadd(v[0], t); y[4] = csub(v[0], t);
    t = c8p(v[5]); y[1] = cadd(v[1], t); y[5] = csub(v[1], t);
    t = cni(v[6]); y[2] = cadd(v[2], t); y[6] = csub(v[2], t);
    t = c8m(v[7]); y[3] = cadd(v[3], t); y[7] = csub(v[3], t);
}
__device__ __forceinline__ void dif4(c32 y[4]) {
    c32 u0 = cadd(y[0], y[2]), d0 = csub(y[0], y[2]);
    c32 u1 = cadd(y[1], y[3]), d1 = cni(csub(y[1], y[3]));
    y[0] = cadd(u0, u1); y[1] = csub(u0, u1);
    y[2] = cadd(d0, d1); y[3] = csub(d0, d1);
}
// DIF radix-4 with twiddles: slots [z0, z2*w^2, z1*w, z3*w^3], w = W_M^{m'}
__device__ __forceinline__ void dif4_tw(c32 y[4], c32 w) {
    c32 w2 = cmul(w, w), w3 = cmul(w2, w);
    c32 s0 = cadd(y[0], y[2]), d0 = csub(y[0], y[2]);
    c32 s1 = cadd(y[1], y[3]), d1 = cni(csub(y[1], y[3]));
    y[0] = cadd(s0, s1);
    y[1] = cmul(csub(s0, s1), w2);
    y[2] = cmul(cadd(d0, d1), w);
    y[3] = cmul(csub(d0, d1), w3);
}
__device__ __forceinline__ void dit4(c32 y[4], c32 w) {
    c32 w2 = cmul(w, w);
    c32 t1 = cmul(y[1], w2); c32 u0 = cadd(y[0], t1), u1 = csub(y[0], t1);
    c32 t3 = cmul(y[3], w2); c32 u2 = cadd(y[2], t3), u3 = csub(y[2], t3);
    c32 s2 = cmul(u2, w);      y[0] = cadd(u0, s2); y[2] = csub(u0, s2);
    c32 s3 = cni(cmul(u3, w)); y[1] = cadd(u1, s3); y[3] = csub(u1, s3);
}

// ---------------- stage1: blocks 0..515 = STFT (8 frames); 516..522 = alpha-FFT; 523 zeroes out.
#define FSTR 546   // frame stride in F (bank-spread for the coalesced writeout reads)
__global__ __launch_bounds__(256) void stage1_kernel(const float* __restrict__ wave,
                                                     const float* __restrict__ win,
                                                     const float* __restrict__ ar,
                                                     const float* __restrict__ ai,
                                                     float2* __restrict__ Ht,
                                                     float2* __restrict__ Afbr,
                                                     float* __restrict__ out) {
    __shared__ float2 S2[4368];      // stft: F[8][546]; afft: X[2112]
    const int tid = threadIdx.x;

    if (blockIdx.x < 516) {
        float2* F = S2;              // [8][FSTR] flattened
        const int w = tid >> 6, l = tid & 63;
        const int b = blockIdx.x / 129;
        const int t0 = (blockIdx.x - b * 129) << 3;
        const float* wb = wave + (size_t)b * LWAV;

        for (int pass = 0; pass < 2; ++pass) {
            const int j = w + (pass << 2);
            const int t = t0 + j;
            if (t < T_FRAMES) {
                c32 y[8];
#pragma unroll
                for (int k = 0; k < 8; ++k) {
                    int s = l + (k << 6);
                    int posn = t * 128 + s - 256;
                    int ix = posn < 0 ? -posn : (posn >= LWAV ? 2 * LWAV - 2 - posn : posn);
                    y[k] = mkc(wb[ix] * win[s], 0.f);
                }
                dif8_tw(y, wexp(l << 2));
#pragma unroll
                for (int k = 0; k < 8; ++k) st2(F, j*FSTR + pS2(l + (k << 6)), y[k]);
                __builtin_amdgcn_wave_barrier();
                {
                    int base = ((l >> 3) << 6) + (l & 7);
#pragma unroll
                    for (int k = 0; k < 8; ++k) y[k] = ld2(F, j*FSTR + pS2(base + (k << 3)));
                    dif8_tw(y, wexp((l & 7) << 5));
#pragma unroll
                    for (int k = 0; k < 8; ++k) st2(F, j*FSTR + pS2(base + (k << 3)), y[k]);
                }
                __builtin_amdgcn_wave_barrier();
                {
#pragma unroll
                    for (int k = 0; k < 8; ++k) y[k] = ld2(F, j*FSTR + pS2((l << 3) + k));
                    dif8_nt(y);
#pragma unroll
                    for (int k = 0; k < 8; ++k) st2(F, j*FSTR + pS2((l << 3) + k), y[k]);
                }
            }
        }
        __syncthreads();
        // Coalesced writeout: needed rows (bin<=256) are exactly {even p} U {p=1}.
        const int jj = tid & 7;          // time offset
        const int rb = tid >> 3;         // row sub-index 0..31
        const bool tok = (t0 + jj < T_FRAMES);
        if (tok) {
#pragma unroll
            for (int rr = 0; rr < 8; ++rr) {
                int p = ((rr << 5) + rb) << 1;                       // even rows
                Ht[(size_t)(b * 512 + p) * TSTRIDE + t0 + jj] = F[jj*FSTR + pS2(p)];
            }
            if (tid < 8)
                Ht[(size_t)(b * 512 + 1) * TSTRIDE + t0 + jj] = F[jj*FSTR + pS2(1)];
        }
    } else if (blockIdx.x < 523) {
        // ---- alpha FFT (storage order = bitrev11). Writeout PERMUTED so conv's
        // pointwise reads are lane-contiguous (coalesced): float4 slot
        // s = wv*256 + kk*64 + (r*8+c)  for old j4 = wv*256 + r*32 + c*4 + kk.
        float2* X = S2;
        const int q = blockIdx.x - 516;
        c32 y[8];
#pragma unroll
        for (int k = 0; k < 8; ++k) {
            int j = tid + (k << 8);
            y[k] = (j < KWC) ? mkc(ar[q * KWC + j], -ai[q * KWC + j]) : mkc(0.f, 0.f);
        }
        dif8_tw(y, wexp(tid));
#pragma unroll
        for (int k = 0; k < 8; ++k) st2(X, pX(tid + (k << 8)), y[k]);
        __syncthreads();
        {
            int base = ((tid >> 5) << 8) + (tid & 31);
#pragma unroll
            for (int k = 0; k < 8; ++k) y[k] = ld2(X, pX(base + (k << 5)));
            dif8_tw(y, wexp((tid & 31) << 3));
#pragma unroll
            for (int k = 0; k < 8; ++k) st2(X, pX(base + (k << 5)), y[k]);
        }
        __syncthreads();
        {
            int base = ((tid & 63) << 5) + (tid >> 6);
#pragma unroll
            for (int k = 0; k < 8; ++k) y[k] = ld2(X, pX(base + (k << 2)));
            dif8_tw(y, wexp((tid >> 6) << 6));
#pragma unroll
            for (int k = 0; k < 8; ++k) st2(X, pX(base + (k << 2)), y[k]);
        }
        __syncthreads();
#pragma unroll
        for (int h = 0; h < 2; ++h) {
            int g = tid + (h << 8);
            c32 z4[4];
#pragma unroll
            for (int k = 0; k < 4; ++k) z4[k] = ld2(X, pX((g << 2) + k));
            dif4(z4);
#pragma unroll
            for (int k = 0; k < 4; ++k) {
                int jx = (g << 2) + k;
                int j4 = jx >> 1, lo = jx & 1;
                int wv4 = j4 >> 8, rem = j4 & 255;
                int r = rem >> 5, c = (rem >> 2) & 7, kk = rem & 3;
                int s = (wv4 << 8) | (kk << 6) | (r << 3) | c;
                Afbr[(q << 11) + (s << 1) + lo] = make_float2(z4[k].r, -z4[k].i);
            }
        }
    } else {
        if (tid == 0) *out = 0.f;
    }
}

// ---------------- conv: TWO rows per block; radix (8,4,8,8); wave-private mid-phases.
// Tail: plain store of block partial (NO atomics — 514 same-address device atomics
// were serializing kernel retirement at the coherence point). reduce_kernel sums.
__global__ __launch_bounds__(256) void conv_kernel(const float2* __restrict__ Ht,
                                                   const float2* __restrict__ Afbr,
                                                   float* __restrict__ partial) {
    __shared__ float2 S2[4224];   // X0[2112] | X1[2112]
    __shared__ float red[4];
    float2* X0 = S2;
    float2* X1 = S2 + 2112;
    const int tid = threadIdx.x;
    const int l = tid & 63, wv = tid >> 6;
    const int g = blockIdx.x;                    // 0..513
    const int half = g / 257;
    const int n = g - half * 257;                // bin 0..256
    const int b0 = half << 1;
    const int pr = rev9(n);                      // Ht row holding bin n

    const float2* row0 = Ht + (size_t)(b0 * 512 + pr) * TSTRIDE;
    const float2* row1 = Ht + (size_t)((b0 + 1) * 512 + pr) * TSTRIDE;

    // twiddles (5 sincos total; shared forward/inverse)
    const c32 wA  = wexp(tid);              // P1 (M=2048) and i4
    const c32 wB  = wexp((l & 31) << 3);    // P2 (M=256, g0) and i3
    const c32 wP3 = wexp((l & 7) << 5);     // P3 (M=64)
    const c32 wI2 = wexp((l & 3) << 6);     // i2 (M=32, g0)

    c32 y0[8], y1[8];
    // ---- P1: load + radix-8 (strides 1024/512/256) in-reg
#pragma unroll
    for (int k = 0; k < 4; ++k) {
        float2 h0 = row0[tid + (k << 8)]; y0[k] = mkc(h0.x, h0.y);
        float2 h1 = row1[tid + (k << 8)]; y1[k] = mkc(h1.x, h1.y);
    }
    if (tid == 0) {
        float2 h0 = row0[1024]; y0[4] = mkc(h0.x, h0.y);
        float2 h1 = row1[1024]; y1[4] = mkc(h1.x, h1.y);
    } else { y0[4] = mkc(0.f, 0.f); y1[4] = mkc(0.f, 0.f); }
#pragma unroll
    for (int k = 5; k < 8; ++k) { y0[k] = mkc(0.f, 0.f); y1[k] = mkc(0.f, 0.f); }
    dif8_tw(y0, wA);
    dif8_tw(y1, wA);
#pragma unroll
    for (int k = 0; k < 8; ++k) {
        int p = pX(tid + (k << 8));
        st2(X0, p, y0[k]); st2(X1, p, y1[k]);
    }
    __syncthreads();                                   // block barrier #1

    // ---- hoisted Afbr prefetch (coalesced: lane-stride 16B). Used in pointwise.
    const float4* af4 = (const float4*)Afbr;
    const int abase = (wv << 8) + l;
    float4 A[4][7];
#pragma unroll
    for (int kk = 0; kk < 4; ++kk)
#pragma unroll
        for (int qq = 0; qq < 7; ++qq)
            A[kk][qq] = af4[(qq << 10) + abase + (kk << 6)];

    // ---- P2: radix-4 (strides 128/64); wave-local from here on
    const int Bb = (((wv << 1) + (l >> 5)) << 8) + (l & 31);   // B*256 + m'
#pragma unroll
    for (int gg = 0; gg < 2; ++gg)
#pragma unroll
        for (int t = 0; t < 4; ++t) {
            int p = pX(Bb + (gg << 5) + (t << 6));
            y0[gg*4+t] = ld2(X0, p); y1[gg*4+t] = ld2(X1, p);
        }
    {
        c32 wg1 = c8p(wB);
        dif4_tw(&y0[0], wB); dif4_tw(&y0[4], wg1);
        dif4_tw(&y1[0], wB); dif4_tw(&y1[4], wg1);
    }
#pragma unroll
    for (int gg = 0; gg < 2; ++gg)
#pragma unroll
        for (int t = 0; t < 4; ++t) {
            int p = pX(Bb + (gg << 5) + (t << 6));
            st2(X0, p, y0[gg*4+t]); st2(X1, p, y1[gg*4+t]);
        }
    __builtin_amdgcn_wave_barrier();

    // ---- P3: radix-8 (strides 32/16/8) within wave's 512-chunk
    const int chunk = wv << 9;
    const int p3b = chunk + ((l >> 3) << 6) + (l & 7);
#pragma unroll
    for (int u = 0; u < 8; ++u) {
        int p = pX(p3b + (u << 3));
        y0[u] = ld2(X0, p); y1[u] = ld2(X1, p);
    }
    dif8_tw(y0, wP3);
    dif8_tw(y1, wP3);
#pragma unroll
    for (int u = 0; u < 8; ++u) {
        int p = pX(p3b + (u << 3));
        st2(X0, p, y0[u]); st2(X1, p, y1[u]);
    }
    __builtin_amdgcn_wave_barrier();

    // ---- P4 (contiguous radix-8) + pointwise Kk + iP4, all in-reg
    const int pos0 = chunk + ((l >> 3) << 6) + ((l & 7) << 3);
    const int px0 = pX(pos0);                          // pos0..pos0+7 contiguous after pad
#pragma unroll
    for (int u = 0; u < 8; ++u) { y0[u] = ld2(X0, px0 + u); y1[u] = ld2(X1, px0 + u); }
    dif8_nt(y0);
    dif8_nt(y1);
    {
        c32 p1 = wexp(-(n << 2));                      // e^{+2pi i n/512}
        c32 p2 = cmul(p1, p1);
        c32 p3 = cmul(p2, p1);
#pragma unroll
        for (int k = 0; k < 8; ++k) {
            const int kk = k >> 1;
            float4 a;
            c32 Kk;
            a = A[kk][3];                      // q'=0
            float ax = (k & 1) ? a.z : a.x, ay = (k & 1) ? a.w : a.y;
            Kk = mkc(ax, ay);
            a = A[kk][4]; ax = (k & 1) ? a.z : a.x; ay = (k & 1) ? a.w : a.y;
            Kk.r += p1.r * ax - p1.i * ay;  Kk.i += p1.r * ay + p1.i * ax;
            a = A[kk][2]; ax = (k & 1) ? a.z : a.x; ay = (k & 1) ? a.w : a.y;
            Kk.r += p1.r * ax + p1.i * ay;  Kk.i += p1.r * ay - p1.i * ax;
            a = A[kk][5]; ax = (k & 1) ? a.z : a.x; ay = (k & 1) ? a.w : a.y;
            Kk.r += p2.r * ax - p2.i * ay;  Kk.i += p2.r * ay + p2.i * ax;
            a = A[kk][1]; ax = (k & 1) ? a.z : a.x; ay = (k & 1) ? a.w : a.y;
            Kk.r += p2.r * ax + p2.i * ay;  Kk.i += p2.r * ay - p2.i * ax;
            a = A[kk][6]; ax = (k & 1) ? a.z : a.x; ay = (k & 1) ? a.w : a.y;
            Kk.r += p3.r * ax - p3.i * ay;  Kk.i += p3.r * ay + p3.i * ax;
            a = A[kk][0]; ax = (k & 1) ? a.z : a.x; ay = (k & 1) ? a.w : a.y;
            Kk.r += p3.r * ax + p3.i * ay;  Kk.i += p3.r * ay - p3.i * ax;
            c32 P0 = cmul(y0[k], Kk);
            c32 P1 = cmul(y1[k], Kk);
            y0[k] = mkc(P0.r, -P0.i);          // conj for inverse-via-forward
            y1[k] = mkc(P1.r, -P1.i);
        }
    }
    dit8_nt(y0);
    dit8_nt(y1);
#pragma unroll
    for (int u = 0; u < 8; ++u) { st2(X0, px0 + u, y0[u]); st2(X1, px0 + u, y1[u]); }
    __builtin_amdgcn_wave_barrier();

    // ---- i2: radix-4 merge (8 -> 32) within wave chunk
    const int i2b = chunk + ((l >> 2) << 5) + (l & 3);
#pragma unroll
    for (int gg = 0; gg < 2; ++gg)
#pragma unroll
        for (int t = 0; t < 4; ++t) {
            int p = pX(i2b + (gg << 2) + (t << 3));
            y0[gg*4+t] = ld2(X0, p); y1[gg*4+t] = ld2(X1, p);
        }
    {
        c32 wg1 = c8p(wI2);
        dit4(&y0[0], wI2); dit4(&y0[4], wg1);
        dit4(&y1[0], wI2); dit4(&y1[4], wg1);
    }
#pragma unroll
    for (int gg = 0; gg < 2; ++gg)
#pragma unroll
        for (int t = 0; t < 4; ++t) {
            int p = pX(i2b + (gg << 2) + (t << 3));
            st2(X0, p, y0[gg*4+t]); st2(X1, p, y1[gg*4+t]);
        }
    __builtin_amdgcn_wave_barrier();

    // ---- i3: radix-8 merge (32 -> 256) within wave chunk
    const int i3b = chunk + ((l >> 5) << 8) + (l & 31);
#pragma unroll
    for (int k = 0; k < 8; ++k) {
        int p = pX(i3b + (k << 5));
        y0[k] = ld2(X0, p); y1[k] = ld2(X1, p);
    }
    dit8_tw(y0, wB);
    dit8_tw(y1, wB);
#pragma unroll
    for (int k = 0; k < 8; ++k) {
        int p = pX(i3b + (k << 5));
        st2(X0, p, y0[k]); st2(X1, p, y1[k]);
    }
    __syncthreads();                                   // block barrier #2

    // ---- i4: radix-8 merge (256 -> 2048) + masked |.|^2
#pragma unroll
    for (int k = 0; k < 8; ++k) {
        int p = pX(tid + (k << 8));
        y0[k] = ld2(X0, p); y1[k] = ld2(X1, p);
    }
    dit8_tw(y0, wA);
    dit8_tw(y1, wA);
    // outputs natural: element k holds c[tid + 256k]; keep s in [0,513] U [1537,2047]
    float local = y0[0].r*y0[0].r + y0[0].i*y0[0].i + y1[0].r*y1[0].r + y1[0].i*y1[0].i
                + y0[1].r*y0[1].r + y0[1].i*y0[1].i + y1[1].r*y1[1].r + y1[1].i*y1[1].i
                + y0[7].r*y0[7].r + y0[7].i*y0[7].i + y1[7].r*y1[7].r + y1[7].i*y1[7].i;
    if (tid < 2)  local += y0[2].r*y0[2].r + y0[2].i*y0[2].i + y1[2].r*y1[2].r + y1[2].i*y1[2].i;
    if (tid >= 1) local += y0[6].r*y0[6].r + y0[6].i*y0[6].i + y1[6].r*y1[6].r + y1[6].i*y1[6].i;

    local *= (n == 0 || n == 256) ? 1.0f : 2.0f;       // mirror-row weight
#pragma unroll
    for (int off = 32; off >= 1; off >>= 1) local += __shfl_down(local, off);
    if ((tid & 63) == 0) red[tid >> 6] = local;
    __syncthreads();                                   // block barrier #3
    if (tid == 0) partial[g] = red[0] + red[1] + red[2] + red[3];   // plain store, no atomic
}

// ---------------- reduce: one block sums 514 partials (contiguous, coalesced).
__global__ __launch_bounds__(256) void reduce_kernel(const float* __restrict__ partial,
                                                     float* __restrict__ out) {
    __shared__ float red[4];
    const int tid = threadIdx.x;
    float s = 0.f;
    for (int i = tid; i < NCONVBLK; i += 256) s += partial[i];
#pragma unroll
    for (int off = 32; off >= 1; off >>= 1) s += __shfl_down(s, off);
    if ((tid & 63) == 0) red[tid >> 6] = s;
    __syncthreads();
    if (tid == 0) {
        const float SCALE =
            (float)(1.0 / ((double)MFFT * (double)MFFT * (double)BATCH * (double)T_FRAMES));
        *out = (red[0] + red[1] + red[2] + red[3]) * SCALE;
    }
}

extern "C" void kernel_launch(void* const* d_in, const int* in_sizes, int n_in,
                              void* d_out, int out_size, void* d_ws, size_t ws_size,
                              hipStream_t stream) {
    (void)in_sizes; (void)n_in; (void)out_size; (void)ws_size;
    const float* wave   = (const float*)d_in[0];
    const float* window = (const float*)d_in[1];
    const float* ar     = (const float*)d_in[2];
    const float* ai     = (const float*)d_in[3];
    float* out = (float*)d_out;

    char* ws = (char*)d_ws;
    float2* Ht      = (float2*)ws;                       // 4*512*1032*8 = 16,908,288 B
    float2* Afbr    = (float2*)(ws + 16908288);          // 7*2048*8    =    114,688 B -> ends 17,022,976
    float*  partial = (float*)(ws + 17022976);           // 514 floats

    stage1_kernel<<<524, 256, 0, stream>>>(wave, window, ar, ai, Ht, Afbr, out);
    conv_kernel<<<2 * 257, 256, 0, stream>>>(Ht, Afbr, partial);
    reduce_kernel<<<1, 256, 0, stream>>>(partial, out);
}

// Round 7
// 84.753 us; speedup vs baseline: 1.0358x; 1.0358x over previous
//
#include <hip/hip_runtime.h>
#include <math.h>

#define T_FRAMES 1025
#define TSTRIDE  1032          // row stride for Ht; 1032*8 = 129*64 -> rows 64B-aligned
#define BATCH    4
#define LWAV     131072
#define KWC      1023
#define MFFT     2048
#define PI_F     3.14159265358979323846f

struct c32 { float r, i; };
__device__ __forceinline__ c32 mkc(float r, float i){ c32 z; z.r=r; z.i=i; return z; }
__device__ __forceinline__ c32 cadd(c32 a, c32 b){ return mkc(a.r+b.r, a.i+b.i); }
__device__ __forceinline__ c32 csub(c32 a, c32 b){ return mkc(a.r-b.r, a.i-b.i); }
__device__ __forceinline__ c32 cmul(c32 a, c32 b){ return mkc(a.r*b.r - a.i*b.i, a.r*b.i + a.i*b.r); }
__device__ __forceinline__ c32 cni(c32 a){ return mkc(a.i, -a.r); }           // a * (-i)
#define C8F 0.70710678118654752440f
__device__ __forceinline__ c32 c8p(c32 a){ return mkc(C8F*(a.r+a.i), C8F*(a.i-a.r)); }   // * e^{-i pi/4}
__device__ __forceinline__ c32 c8m(c32 a){ return mkc(C8F*(a.i-a.r), -C8F*(a.r+a.i)); }  // * e^{-i 3pi/4}

// float2 <-> c32 LDS helpers
__device__ __forceinline__ void st2(float2* X, int p, c32 v){ X[p] = make_float2(v.r, v.i); }
__device__ __forceinline__ c32 ld2(const float2* X, int p){ float2 e = X[p]; return mkc(e.x, e.y); }

// pads: pX for 2048-FFT arrays; pS2 for 512-FFT frames
__device__ __forceinline__ int pX(int j){ return j + (j >> 5); }
__device__ __forceinline__ int pS2(int j){ return j + (j >> 4); }
__device__ __forceinline__ int rev9(int j){ return (int)(__brev((unsigned)j) >> 23); }

// e^{-2*pi*i*r/2048} via fast HW sincos
__device__ __forceinline__ c32 wexp(int r) {
    float s, c;
    __sincosf((float)r * (-PI_F / 1024.0f), &s, &c);
    return mkc(c, s);
}

// ---- radix-8 DIF step; w3 = W_M^{m'} of current level (M = sub-size)
__device__ __forceinline__ void dif8_tw(c32 y[8], c32 w3) {
    c32 w2 = cmul(w3, w3), w1 = cmul(w2, w2);
    c32 u[8], v[8], d;
    d = csub(y[0], y[4]); u[0] = cadd(y[0], y[4]); u[4] = cmul(d, w3);
    d = csub(y[1], y[5]); u[1] = cadd(y[1], y[5]); u[5] = c8p(cmul(d, w3));
    d = csub(y[2], y[6]); u[2] = cadd(y[2], y[6]); u[6] = cni(cmul(d, w3));
    d = csub(y[3], y[7]); u[3] = cadd(y[3], y[7]); u[7] = c8m(cmul(d, w3));
    d = csub(u[0], u[2]); v[0] = cadd(u[0], u[2]); v[2] = cmul(d, w2);
    d = csub(u[1], u[3]); v[1] = cadd(u[1], u[3]); v[3] = cni(cmul(d, w2));
    d = csub(u[4], u[6]); v[4] = cadd(u[4], u[6]); v[6] = cmul(d, w2);
    d = csub(u[5], u[7]); v[5] = cadd(u[5], u[7]); v[7] = cni(cmul(d, w2));
    d = csub(v[0], v[1]); y[0] = cadd(v[0], v[1]); y[1] = cmul(d, w1);
    d = csub(v[2], v[3]); y[2] = cadd(v[2], v[3]); y[3] = cmul(d, w1);
    d = csub(v[4], v[5]); y[4] = cadd(v[4], v[5]); y[5] = cmul(d, w1);
    d = csub(v[6], v[7]); y[6] = cadd(v[6], v[7]); y[7] = cmul(d, w1);
}
__device__ __forceinline__ void dif8_nt(c32 y[8]) {
    c32 u[8], v[8], d;
    d = csub(y[0], y[4]); u[0] = cadd(y[0], y[4]); u[4] = d;
    d = csub(y[1], y[5]); u[1] = cadd(y[1], y[5]); u[5] = c8p(d);
    d = csub(y[2], y[6]); u[2] = cadd(y[2], y[6]); u[6] = cni(d);
    d = csub(y[3], y[7]); u[3] = cadd(y[3], y[7]); u[7] = c8m(d);
    d = csub(u[0], u[2]); v[0] = cadd(u[0], u[2]); v[2] = d;
    d = csub(u[1], u[3]); v[1] = cadd(u[1], u[3]); v[3] = cni(d);
    d = csub(u[4], u[6]); v[4] = cadd(u[4], u[6]); v[6] = d;
    d = csub(u[5], u[7]); v[5] = cadd(u[5], u[7]); v[7] = cni(d);
    d = csub(v[0], v[1]); y[0] = cadd(v[0], v[1]); y[1] = d;
    d = csub(v[2], v[3]); y[2] = cadd(v[2], v[3]); y[3] = d;
    d = csub(v[4], v[5]); y[4] = cadd(v[4], v[5]); y[5] = d;
    d = csub(v[6], v[7]); y[6] = cadd(v[6], v[7]); y[7] = d;
}
__device__ __forceinline__ void dit8_tw(c32 y[8], c32 w3) {
    c32 w2 = cmul(w3, w3), w1 = cmul(w2, w2);
    c32 u[8], v[8], t;
    t = cmul(y[1], w1); u[0] = cadd(y[0], t); u[1] = csub(y[0], t);
    t = cmul(y[3], w1); u[2] = cadd(y[2], t); u[3] = csub(y[2], t);
    t = cmul(y[5], w1); u[4] = cadd(y[4], t); u[5] = csub(y[4], t);
    t = cmul(y[7], w1); u[6] = cadd(y[6], t); u[7] = csub(y[6], t);
    t = cmul(u[2], w2);      v[0] = cadd(u[0], t); v[2] = csub(u[0], t);
    t = cni(cmul(u[3], w2)); v[1] = cadd(u[1], t); v[3] = csub(u[1], t);
    t = cmul(u[6], w2);      v[4] = cadd(u[4], t); v[6] = csub(u[4], t);
    t = cni(cmul(u[7], w2)); v[5] = cadd(u[5], t); v[7] = csub(u[5], t);
    t = cmul(v[4], w3);      y[0] = cadd(v[0], t); y[4] = csub(v[0], t);
    t = c8p(cmul(v[5], w3)); y[1] = cadd(v[1], t); y[5] = csub(v[1], t);
    t = cni(cmul(v[6], w3)); y[2] = cadd(v[2], t); y[6] = csub(v[2], t);
    t = c8m(cmul(v[7], w3)); y[3] = cadd(v[3], t); y[7] = csub(v[3], t);
}
__device__ __forceinline__ void dit8_nt(c32 y[8]) {
    c32 u[8], v[8], t;
    u[0] = cadd(y[0], y[1]); u[1] = csub(y[0], y[1]);
    u[2] = cadd(y[2], y[3]); u[3] = csub(y[2], y[3]);
    u[4] = cadd(y[4], y[5]); u[5] = csub(y[4], y[5]);
    u[6] = cadd(y[6], y[7]); u[7] = csub(y[6], y[7]);
    t = u[2];      v[0] = cadd(u[0], t); v[2] = csub(u[0], t);
    t = cni(u[3]); v[1] = cadd(u[1], t); v[3] = csub(u[1], t);
    t = u[6];      v[4] = cadd(u[4], t); v[6] = csub(u[4], t);
    t = cni(u[7]); v[5] = cadd(u[5], t); v[7] = csub(u[5], t);
    t = v[4];      y[0] = cadd(v[0], t); y[4] = csub(v[0], t);
    t = c8p(v[5]); y[1] = cadd(v[1], t); y[5] = csub(v[1], t);
    t = cni(v[6]); y[2] = cadd(v[2], t); y[6] = csub(v[2], t);
    t = c8m(v[7]); y[3] = cadd(v[3], t); y[7] = csub(v[3], t);
}
__device__ __forceinline__ void dif4(c32 y[4]) {
    c32 u0 = cadd(y[0], y[2]), d0 = csub(y[0], y[2]);
    c32 u1 = cadd(y[1], y[3]), d1 = cni(csub(y[1], y[3]));
    y[0] = cadd(u0, u1); y[1] = csub(u0, u1);
    y[2] = cadd(d0, d1); y[3] = csub(d0, d1);
}
// DIF radix-4 with twiddles: slots [z0, z2*w^2, z1*w, z3*w^3], w = W_M^{m'}
__device__ __forceinline__ void dif4_tw(c32 y[4], c32 w) {
    c32 w2 = cmul(w, w), w3 = cmul(w2, w);
    c32 s0 = cadd(y[0], y[2]), d0 = csub(y[0], y[2]);
    c32 s1 = cadd(y[1], y[3]), d1 = cni(csub(y[1], y[3]));
    y[0] = cadd(s0, s1);
    y[1] = cmul(csub(s0, s1), w2);
    y[2] = cmul(cadd(d0, d1), w);
    y[3] = cmul(csub(d0, d1), w3);
}
__device__ __forceinline__ void dit4(c32 y[4], c32 w) {
    c32 w2 = cmul(w, w);
    c32 t1 = cmul(y[1], w2); c32 u0 = cadd(y[0], t1), u1 = csub(y[0], t1);
    c32 t3 = cmul(y[3], w2); c32 u2 = cadd(y[2], t3), u3 = csub(y[2], t3);
    c32 s2 = cmul(u2, w);      y[0] = cadd(u0, s2); y[2] = csub(u0, s2);
    c32 s3 = cni(cmul(u3, w)); y[1] = cadd(u1, s3); y[3] = csub(u1, s3);
}

// ---------------- stage1: blocks 0..515 = STFT (8 frames); 516..522 = alpha-FFT; 523 zeroes out.
#define FSTR 546   // frame stride in F (bank-spread for the coalesced writeout reads)
__global__ __launch_bounds__(256) void stage1_kernel(const float* __restrict__ wave,
                                                     const float* __restrict__ win,
                                                     const float* __restrict__ ar,
                                                     const float* __restrict__ ai,
                                                     float2* __restrict__ Ht,
                                                     float2* __restrict__ Afbr,
                                                     float* __restrict__ out) {
    __shared__ float2 S2[4368];      // stft: F[8][546]; afft: X[2112]
    const int tid = threadIdx.x;

    if (blockIdx.x < 516) {
        float2* F = S2;              // [8][FSTR] flattened
        const int w = tid >> 6, l = tid & 63;
        const int b = blockIdx.x / 129;
        const int t0 = (blockIdx.x - b * 129) << 3;
        const float* wb = wave + (size_t)b * LWAV;

        for (int pass = 0; pass < 2; ++pass) {
            const int j = w + (pass << 2);
            const int t = t0 + j;
            if (t < T_FRAMES) {
                c32 y[8];
#pragma unroll
                for (int k = 0; k < 8; ++k) {
                    int s = l + (k << 6);
                    int posn = t * 128 + s - 256;
                    int ix = posn < 0 ? -posn : (posn >= LWAV ? 2 * LWAV - 2 - posn : posn);
                    y[k] = mkc(wb[ix] * win[s], 0.f);
                }
                dif8_tw(y, wexp(l << 2));
#pragma unroll
                for (int k = 0; k < 8; ++k) st2(F, j*FSTR + pS2(l + (k << 6)), y[k]);
                __builtin_amdgcn_wave_barrier();
                {
                    int base = ((l >> 3) << 6) + (l & 7);
#pragma unroll
                    for (int k = 0; k < 8; ++k) y[k] = ld2(F, j*FSTR + pS2(base + (k << 3)));
                    dif8_tw(y, wexp((l & 7) << 5));
#pragma unroll
                    for (int k = 0; k < 8; ++k) st2(F, j*FSTR + pS2(base + (k << 3)), y[k]);
                }
                __builtin_amdgcn_wave_barrier();
                {
#pragma unroll
                    for (int k = 0; k < 8; ++k) y[k] = ld2(F, j*FSTR + pS2((l << 3) + k));
                    dif8_nt(y);
#pragma unroll
                    for (int k = 0; k < 8; ++k) st2(F, j*FSTR + pS2((l << 3) + k), y[k]);
                }
            }
        }
        __syncthreads();
        // Coalesced writeout: needed rows (bin<=256) are exactly {even p} U {p=1}.
        const int jj = tid & 7;          // time offset
        const int rb = tid >> 3;         // row sub-index 0..31
        const bool tok = (t0 + jj < T_FRAMES);
        if (tok) {
#pragma unroll
            for (int rr = 0; rr < 8; ++rr) {
                int p = ((rr << 5) + rb) << 1;                       // even rows
                Ht[(size_t)(b * 512 + p) * TSTRIDE + t0 + jj] = F[jj*FSTR + pS2(p)];
            }
            if (tid < 8)
                Ht[(size_t)(b * 512 + 1) * TSTRIDE + t0 + jj] = F[jj*FSTR + pS2(1)];
        }
    } else if (blockIdx.x < 523) {
        // ---- alpha FFT (storage order = bitrev11). Writeout PERMUTED so conv's
        // pointwise reads are lane-contiguous (coalesced).
        float2* X = S2;
        const int q = blockIdx.x - 516;
        c32 y[8];
#pragma unroll
        for (int k = 0; k < 8; ++k) {
            int j = tid + (k << 8);
            y[k] = (j < KWC) ? mkc(ar[q * KWC + j], -ai[q * KWC + j]) : mkc(0.f, 0.f);
        }
        dif8_tw(y, wexp(tid));
#pragma unroll
        for (int k = 0; k < 8; ++k) st2(X, pX(tid + (k << 8)), y[k]);
        __syncthreads();
        {
            int base = ((tid >> 5) << 8) + (tid & 31);
#pragma unroll
            for (int k = 0; k < 8; ++k) y[k] = ld2(X, pX(base + (k << 5)));
            dif8_tw(y, wexp((tid & 31) << 3));
#pragma unroll
            for (int k = 0; k < 8; ++k) st2(X, pX(base + (k << 5)), y[k]);
        }
        __syncthreads();
        {
            int base = ((tid & 63) << 5) + (tid >> 6);
#pragma unroll
            for (int k = 0; k < 8; ++k) y[k] = ld2(X, pX(base + (k << 2)));
            dif8_tw(y, wexp((tid >> 6) << 6));
#pragma unroll
            for (int k = 0; k < 8; ++k) st2(X, pX(base + (k << 2)), y[k]);
        }
        __syncthreads();
#pragma unroll
        for (int h = 0; h < 2; ++h) {
            int g = tid + (h << 8);
            c32 z4[4];
#pragma unroll
            for (int k = 0; k < 4; ++k) z4[k] = ld2(X, pX((g << 2) + k));
            dif4(z4);
#pragma unroll
            for (int k = 0; k < 4; ++k) {
                int jx = (g << 2) + k;
                int j4 = jx >> 1, lo = jx & 1;
                int wv4 = j4 >> 8, rem = j4 & 255;
                int r = rem >> 5, c = (rem >> 2) & 7, kk = rem & 3;
                int s = (wv4 << 8) | (kk << 6) | (r << 3) | c;
                Afbr[(q << 11) + (s << 1) + lo] = make_float2(z4[k].r, -z4[k].i);
            }
        }
    } else {
        if (tid == 0) *out = 0.f;
    }
}

// ---------------- conv: TWO rows per block, but the row dimension is a ROLLED
// `#pragma unroll 1` loop in every phase -> ~half the code footprint (I$ fits).
// Each phase starts/ends in LDS so per-row state is loop-local (no runtime-
// indexed register arrays). Twiddles hoisted; Kk rebuilt per row (small VALU cost).
__global__ __launch_bounds__(256) void conv_kernel(const float2* __restrict__ Ht,
                                                   const float2* __restrict__ Afbr,
                                                   float* __restrict__ out) {
    __shared__ float2 S2[4224];   // X0[2112] | X1[2112]
    __shared__ float red[4];
    const int tid = threadIdx.x;
    const int l = tid & 63, wv = tid >> 6;
    const int g = blockIdx.x;                    // 0..513
    const int half = g / 257;
    const int n = g - half * 257;                // bin 0..256
    const int b0 = half << 1;
    const int pr = rev9(n);                      // Ht row holding bin n

    // twiddles (shared forward/inverse, hoisted out of the row loops)
    const c32 wA  = wexp(tid);              // P1 (M=2048) and i4
    const c32 wB  = wexp((l & 31) << 3);    // P2 (M=256, g0) and i3
    const c32 wP3 = wexp((l & 7) << 5);     // P3 (M=64)
    const c32 wI2 = wexp((l & 3) << 6);     // i2 (M=32, g0)
    const c32 wg1B = c8p(wB);
    const c32 wg1I = c8p(wI2);
    const c32 p1 = wexp(-(n << 2));         // e^{+2pi i n/512}
    const c32 p2 = cmul(p1, p1);
    const c32 p3 = cmul(p2, p1);

    // index bases (loop-invariant)
    const int Bb   = (((wv << 1) + (l >> 5)) << 8) + (l & 31);
    const int chunk = wv << 9;
    const int p3b  = chunk + ((l >> 3) << 6) + (l & 7);
    const int pos0 = chunk + ((l >> 3) << 6) + ((l & 7) << 3);
    const int px0  = pX(pos0);
    const int i2b  = chunk + ((l >> 2) << 5) + (l & 3);
    const int i3b  = chunk + ((l >> 5) << 8) + (l & 31);
    const int abase = (wv << 8) + l;
    const float4* af4 = (const float4*)Afbr;

    // ---- P1: load + radix-8 (strides 1024/512/256)
#pragma unroll 1
    for (int r = 0; r < 2; ++r) {
        const float2* row = Ht + (size_t)((b0 + r) * 512 + pr) * TSTRIDE;
        float2* X = S2 + r * 2112;
        c32 y[8];
#pragma unroll
        for (int k = 0; k < 4; ++k) { float2 h = row[tid + (k << 8)]; y[k] = mkc(h.x, h.y); }
        if (tid == 0) { float2 h = row[1024]; y[4] = mkc(h.x, h.y); } else y[4] = mkc(0.f, 0.f);
        y[5] = mkc(0.f, 0.f); y[6] = mkc(0.f, 0.f); y[7] = mkc(0.f, 0.f);
        dif8_tw(y, wA);
#pragma unroll
        for (int k = 0; k < 8; ++k) st2(X, pX(tid + (k << 8)), y[k]);
    }
    __syncthreads();                                   // block barrier #1

    // ---- P2: radix-4 (strides 128/64); wave-local from here on
#pragma unroll 1
    for (int r = 0; r < 2; ++r) {
        float2* X = S2 + r * 2112;
        c32 y[8];
#pragma unroll
        for (int gg = 0; gg < 2; ++gg)
#pragma unroll
            for (int t = 0; t < 4; ++t) y[gg*4+t] = ld2(X, pX(Bb + (gg << 5) + (t << 6)));
        dif4_tw(&y[0], wB); dif4_tw(&y[4], wg1B);
#pragma unroll
        for (int gg = 0; gg < 2; ++gg)
#pragma unroll
            for (int t = 0; t < 4; ++t) st2(X, pX(Bb + (gg << 5) + (t << 6)), y[gg*4+t]);
    }
    __builtin_amdgcn_wave_barrier();

    // ---- P3: radix-8 (strides 32/16/8) within wave's 512-chunk
#pragma unroll 1
    for (int r = 0; r < 2; ++r) {
        float2* X = S2 + r * 2112;
        c32 y[8];
#pragma unroll
        for (int u = 0; u < 8; ++u) y[u] = ld2(X, pX(p3b + (u << 3)));
        dif8_tw(y, wP3);
#pragma unroll
        for (int u = 0; u < 8; ++u) st2(X, pX(p3b + (u << 3)), y[u]);
    }
    __builtin_amdgcn_wave_barrier();

    // ---- P4 (contiguous radix-8) + pointwise Kk + iP4
#pragma unroll 1
    for (int r = 0; r < 2; ++r) {
        float2* X = S2 + r * 2112;
        c32 y[8];
#pragma unroll
        for (int u = 0; u < 8; ++u) y[u] = ld2(X, px0 + u);
        dif8_nt(y);
#pragma unroll
        for (int k = 0; k < 8; ++k) {
            const int kk = k >> 1;
            float4 a;
            c32 Kk;
            a = af4[(3 << 10) + abase + (kk << 6)];     // q'=0
            float ax = (k & 1) ? a.z : a.x, ay = (k & 1) ? a.w : a.y;
            Kk = mkc(ax, ay);
            a = af4[(4 << 10) + abase + (kk << 6)]; ax = (k & 1) ? a.z : a.x; ay = (k & 1) ? a.w : a.y;
            Kk.r += p1.r * ax - p1.i * ay;  Kk.i += p1.r * ay + p1.i * ax;
            a = af4[(2 << 10) + abase + (kk << 6)]; ax = (k & 1) ? a.z : a.x; ay = (k & 1) ? a.w : a.y;
            Kk.r += p1.r * ax + p1.i * ay;  Kk.i += p1.r * ay - p1.i * ax;
            a = af4[(5 << 10) + abase + (kk << 6)]; ax = (k & 1) ? a.z : a.x; ay = (k & 1) ? a.w : a.y;
            Kk.r += p2.r * ax - p2.i * ay;  Kk.i += p2.r * ay + p2.i * ax;
            a = af4[(1 << 10) + abase + (kk << 6)]; ax = (k & 1) ? a.z : a.x; ay = (k & 1) ? a.w : a.y;
            Kk.r += p2.r * ax + p2.i * ay;  Kk.i += p2.r * ay - p2.i * ax;
            a = af4[(6 << 10) + abase + (kk << 6)]; ax = (k & 1) ? a.z : a.x; ay = (k & 1) ? a.w : a.y;
            Kk.r += p3.r * ax - p3.i * ay;  Kk.i += p3.r * ay + p3.i * ax;
            a = af4[(0 << 10) + abase + (kk << 6)]; ax = (k & 1) ? a.z : a.x; ay = (k & 1) ? a.w : a.y;
            Kk.r += p3.r * ax + p3.i * ay;  Kk.i += p3.r * ay - p3.i * ax;
            c32 P = cmul(y[k], Kk);
            y[k] = mkc(P.r, -P.i);             // conj for inverse-via-forward
        }
        dit8_nt(y);
#pragma unroll
        for (int u = 0; u < 8; ++u) st2(X, px0 + u, y[u]);
    }
    __builtin_amdgcn_wave_barrier();

    // ---- i2: radix-4 merge (8 -> 32) within wave chunk
#pragma unroll 1
    for (int r = 0; r < 2; ++r) {
        float2* X = S2 + r * 2112;
        c32 y[8];
#pragma unroll
        for (int gg = 0; gg < 2; ++gg)
#pragma unroll
            for (int t = 0; t < 4; ++t) y[gg*4+t] = ld2(X, pX(i2b + (gg << 2) + (t << 3)));
        dit4(&y[0], wI2); dit4(&y[4], wg1I);
#pragma unroll
        for (int gg = 0; gg < 2; ++gg)
#pragma unroll
            for (int t = 0; t < 4; ++t) st2(X, pX(i2b + (gg << 2) + (t << 3)), y[gg*4+t]);
    }
    __builtin_amdgcn_wave_barrier();

    // ---- i3: radix-8 merge (32 -> 256) within wave chunk
#pragma unroll 1
    for (int r = 0; r < 2; ++r) {
        float2* X = S2 + r * 2112;
        c32 y[8];
#pragma unroll
        for (int k = 0; k < 8; ++k) y[k] = ld2(X, pX(i3b + (k << 5)));
        dit8_tw(y, wB);
#pragma unroll
        for (int k = 0; k < 8; ++k) st2(X, pX(i3b + (k << 5)), y[k]);
    }
    __syncthreads();                                   // block barrier #2

    // ---- i4: radix-8 merge (256 -> 2048) + masked |.|^2
    float local = 0.f;
#pragma unroll 1
    for (int r = 0; r < 2; ++r) {
        float2* X = S2 + r * 2112;
        c32 y[8];
#pragma unroll
        for (int k = 0; k < 8; ++k) y[k] = ld2(X, pX(tid + (k << 8)));
        dit8_tw(y, wA);
        // outputs natural: element k holds c[tid + 256k]; keep s in [0,513] U [1537,2047]
        local += y[0].r*y[0].r + y[0].i*y[0].i
               + y[1].r*y[1].r + y[1].i*y[1].i
               + y[7].r*y[7].r + y[7].i*y[7].i;
        if (tid < 2)  local += y[2].r*y[2].r + y[2].i*y[2].i;
        if (tid >= 1) local += y[6].r*y[6].r + y[6].i*y[6].i;
    }
    local *= (n == 0 || n == 256) ? 1.0f : 2.0f;       // mirror-row weight
#pragma unroll
    for (int off = 32; off >= 1; off >>= 1) local += __shfl_down(local, off);
    if ((tid & 63) == 0) red[tid >> 6] = local;
    __syncthreads();                                   // block barrier #3
    if (tid == 0) {
        const float SCALE =
            (float)(1.0 / ((double)MFFT * (double)MFFT * (double)BATCH * (double)T_FRAMES));
        atomicAdd(out, (red[0] + red[1] + red[2] + red[3]) * SCALE);
    }
}

extern "C" void kernel_launch(void* const* d_in, const int* in_sizes, int n_in,
                              void* d_out, int out_size, void* d_ws, size_t ws_size,
                              hipStream_t stream) {
    (void)in_sizes; (void)n_in; (void)out_size; (void)ws_size;
    const float* wave   = (const float*)d_in[0];
    const float* window = (const float*)d_in[1];
    const float* ar     = (const float*)d_in[2];
    const float* ai     = (const float*)d_in[3];
    float* out = (float*)d_out;

    char* ws = (char*)d_ws;
    float2* Ht   = (float2*)ws;                          // 4*512*1032*8 = 16,908,288 B
    float2* Afbr = (float2*)(ws + 16908288);             // 7*2048*8    =    114,688 B

    stage1_kernel<<<524, 256, 0, stream>>>(wave, window, ar, ai, Ht, Afbr, out);
    conv_kernel<<<2 * 257, 256, 0, stream>>>(Ht, Afbr, out);
}